// Round 6
// baseline (196.734 us; speedup 1.0000x reference)
//
#include <hip/hip_runtime.h>

#define N_PTS 65536
#define NSS 16
#define C 64

typedef __attribute__((ext_vector_type(8))) short short8;
typedef __attribute__((ext_vector_type(4))) float f32x4;

__device__ __forceinline__ unsigned short f2bf(float v) {
  unsigned int u = __float_as_uint(v);
  u += 0x7fffu + ((u >> 16) & 1u);  // RNE
  return (unsigned short)(u >> 16);
}
__device__ __forceinline__ float bflo(unsigned int u) { return __uint_as_float(u << 16); }
__device__ __forceinline__ float bfhi(unsigned int u) { return __uint_as_float(u & 0xffff0000u); }

// 16x16x16 morton cell id of a point (p in [0,10])
__device__ __forceinline__ int cell_of(float px, float py, float pz) {
  const int cx = min(15, max(0, (int)(px * 1.6f)));
  const int cy = min(15, max(0, (int)(py * 1.6f)));
  const int cz = min(15, max(0, (int)(pz * 1.6f)));
  int m = 0;
#pragma unroll
  for (int b = 0; b < 4; ++b)
    m |= (((cx >> b) & 1) << (3 * b + 2)) | (((cy >> b) & 1) << (3 * b + 1)) |
         (((cz >> b) & 1) << (3 * b));
  return m;
}

// ---------------- init: wt (QKV weights bf16 transposed), wtq/tb (T-fold), hist ----------------
__global__ __launch_bounds__(256) void init_kernel(
    const float* __restrict__ Wq, const float* __restrict__ Wk, const float* __restrict__ Wv,
    const float* __restrict__ Wp2, const float* __restrict__ bp2, const float* __restrict__ bq,
    const float* __restrict__ p,
    unsigned short* __restrict__ wt, unsigned short* __restrict__ wtq,
    float* __restrict__ tb, int* __restrict__ hist) {
  const int t = blockIdx.x * 256 + threadIdx.x;
  if (t < 192 * 64) {
    const int k = t / 192, ng = t % 192;
    const int mat = ng >> 6, n = ng & 63;
    const float* W = mat == 0 ? Wq : (mat == 1 ? Wk : Wv);
    wt[ng * 64 + k] = f2bf(W[k * 64 + n]);
  }
  if (t < 1024) {  // wtq[row][k] = sum_c Wq[k][c] * B2[row][c], rows 4..15 zero
    const int row = t >> 6, k = t & 63;
    float val = 0.f;
    if (row < 4) {
      const float* B2 = (row == 3) ? bp2 : (Wp2 + row * 64);
      for (int c2 = 0; c2 < 64; ++c2) val += Wq[k * 64 + c2] * B2[c2];
    }
    wtq[t] = f2bf(val);
  }
  if (t >= 1024 && t < 1028) {
    const int n2 = t - 1024;
    const float* B2 = (n2 == 3) ? bp2 : (Wp2 + n2 * 64);
    float val = 0.f;
    for (int c2 = 0; c2 < 64; ++c2) val += bq[c2] * B2[c2];
    tb[n2] = val;
  }
  if (t < N_PTS) {
    atomicAdd(&hist[cell_of(p[t * 3 + 0], p[t * 3 + 1], p[t * 3 + 2])], 1);
  }
}

// ---------------- stats: p_r moments, standalone & lean ----------------
// 262144 threads; each handles 4 consecutive neighbors of point n = tid>>2.
// stats[i*16] padding: each of the 9 accumulators lives in its own cache line.
__global__ __launch_bounds__(256) void stats_kernel(
    const float* __restrict__ p, const int* __restrict__ idx, float* __restrict__ stats) {
  const int tid = blockIdx.x * 256 + threadIdx.x;
  const int n = tid >> 2;
  const int4 j4 = ((const int4*)idx)[tid];
  const float pnx = p[n * 3 + 0], pny = p[n * 3 + 1], pnz = p[n * 3 + 2];
  float s0 = 0, s1 = 0, s2 = 0, s00 = 0, s01 = 0, s02 = 0, s11 = 0, s12 = 0, s22 = 0;
  const int js[4] = {j4.x, j4.y, j4.z, j4.w};
#pragma unroll
  for (int i = 0; i < 4; ++i) {
    const int j = js[i];
    const float dx = p[j * 3 + 0] - pnx;
    const float dy = p[j * 3 + 1] - pny;
    const float dz = p[j * 3 + 2] - pnz;
    s0 += dx; s1 += dy; s2 += dz;
    s00 += dx * dx; s01 += dx * dy; s02 += dx * dz;
    s11 += dy * dy; s12 += dy * dz; s22 += dz * dz;
  }
#pragma unroll
  for (int m = 1; m < 64; m <<= 1) {
    s0 += __shfl_xor(s0, m, 64);  s1 += __shfl_xor(s1, m, 64);  s2 += __shfl_xor(s2, m, 64);
    s00 += __shfl_xor(s00, m, 64); s01 += __shfl_xor(s01, m, 64); s02 += __shfl_xor(s02, m, 64);
    s11 += __shfl_xor(s11, m, 64); s12 += __shfl_xor(s12, m, 64); s22 += __shfl_xor(s22, m, 64);
  }
  __shared__ float part[4][9];
  const int wave = threadIdx.x >> 6, lane = threadIdx.x & 63;
  if (lane == 0) {
    part[wave][0] = s0;  part[wave][1] = s1;  part[wave][2] = s2;
    part[wave][3] = s00; part[wave][4] = s01; part[wave][5] = s02;
    part[wave][6] = s11; part[wave][7] = s12; part[wave][8] = s22;
  }
  __syncthreads();
  if (threadIdx.x < 9) {
    const float acc = part[0][threadIdx.x] + part[1][threadIdx.x] +
                      part[2][threadIdx.x] + part[3][threadIdx.x];
    atomicAdd(&stats[threadIdx.x * 16], acc);
  }
}

// ---------------- QKV via MFMA + T-precompute (GEMM only, no tail) ----------------
// kvq[N][192] bf16 (Q|K|V rows); tq[N][4] fp32
__global__ __launch_bounds__(256) void qkv_gemm(
    const float* __restrict__ x, const unsigned short* __restrict__ wt,
    const unsigned short* __restrict__ wtq, const float* __restrict__ tb,
    const float* __restrict__ bq, const float* __restrict__ bk, const float* __restrict__ bv,
    unsigned short* __restrict__ kvq, float* __restrict__ tq) {
  __shared__ __align__(16) unsigned short xs[64][72];
  __shared__ __align__(16) unsigned short kvs[64][192];  // matches global layout
  const int t = threadIdx.x;
  const int p0 = blockIdx.x * 64;
  const float4* x4 = (const float4*)x;
#pragma unroll
  for (int j = 0; j < 4; ++j) {
    const int id = j * 256 + t;
    const int row = id >> 4, cg = id & 15;
    const float4 v = x4[(p0 + row) * 16 + cg];
    ushort4 h4;
    h4.x = f2bf(v.x); h4.y = f2bf(v.y); h4.z = f2bf(v.z); h4.w = f2bf(v.w);
    *(ushort4*)&xs[row][cg * 4] = h4;
  }
  __syncthreads();

  const int lane = t & 63, wave = t >> 6;
  const int quad = lane >> 4, lr = lane & 15;
  const int mrow = wave * 16 + lr;
  const short8 a0 = *(const short8*)&xs[mrow][quad * 8];
  const short8 a1 = *(const short8*)&xs[mrow][quad * 8 + 32];
#pragma unroll
  for (int nt = 0; nt < 12; ++nt) {
    const unsigned short* bpr = wt + (nt * 16 + lr) * 64 + quad * 8;
    const short8 b0 = *(const short8*)bpr;
    const short8 b1 = *(const short8*)(bpr + 32);
    f32x4 acc = {0.f, 0.f, 0.f, 0.f};
    acc = __builtin_amdgcn_mfma_f32_16x16x32_bf16(a0, b0, acc, 0, 0, 0);
    acc = __builtin_amdgcn_mfma_f32_16x16x32_bf16(a1, b1, acc, 0, 0, 0);
    const int mat = nt >> 2;
    const int c = (nt & 3) * 16 + lr;
    const float bias = (mat == 0 ? bq : (mat == 1 ? bk : bv))[c];
#pragma unroll
    for (int r = 0; r < 4; ++r) {
      const int row = wave * 16 + quad * 4 + r;
      kvs[row][mat * 64 + c] = f2bf(acc[r] + bias);
    }
  }
  {  // T = q . [Wp2 rows | bp2]
    const unsigned short* bpr = wtq + lr * 64 + quad * 8;
    const short8 b0 = *(const short8*)bpr;
    const short8 b1 = *(const short8*)(bpr + 32);
    f32x4 acc = {0.f, 0.f, 0.f, 0.f};
    acc = __builtin_amdgcn_mfma_f32_16x16x32_bf16(a0, b0, acc, 0, 0, 0);
    acc = __builtin_amdgcn_mfma_f32_16x16x32_bf16(a1, b1, acc, 0, 0, 0);
    if (lr < 4) {
      const float tbv = tb[lr];
#pragma unroll
      for (int r = 0; r < 4; ++r) {
        const int pt = p0 + wave * 16 + quad * 4 + r;
        tq[pt * 4 + lr] = acc[r] + tbv;
      }
    }
  }
  __syncthreads();
  // coalesced kvq store: 64 rows x 384 B contiguous = 1536 uint4
  const uint4* kvs4 = (const uint4*)&kvs[0][0];
  uint4* dst = (uint4*)(kvq + (size_t)p0 * 192);
#pragma unroll
  for (int j = 0; j < 6; ++j) dst[j * 256 + t] = kvs4[j * 256 + t];
}

// ---------------- scan (parallel) + BN fold into ebn[12] ----------------
__global__ __launch_bounds__(256) void scan_kernel(
    const int* __restrict__ hist, int* __restrict__ offs,
    const float* __restrict__ stats,
    const float* __restrict__ Wp1, const float* __restrict__ bp1,
    const float* __restrict__ gamma, const float* __restrict__ beta,
    float* __restrict__ ebn) {
  const int t = threadIdx.x;
  const int lane = t & 63, wv = t >> 6;
  int loc[16];
  int sum = 0;
#pragma unroll
  for (int i = 0; i < 16; ++i) { loc[i] = hist[t * 16 + i]; sum += loc[i]; }
  int incl = sum;
#pragma unroll
  for (int off = 1; off < 64; off <<= 1) {
    const int v = __shfl_up(incl, off, 64);
    if (lane >= off) incl += v;
  }
  __shared__ int wtot[4];
  if (lane == 63) wtot[wv] = incl;
  __syncthreads();
  int wbase = 0;
#pragma unroll
  for (int i = 0; i < 4; ++i) wbase += (i < wv) ? wtot[i] : 0;
  int run = wbase + incl - sum;  // exclusive prefix
#pragma unroll
  for (int i = 0; i < 16; ++i) { offs[t * 16 + i] = run; run += loc[i]; }

  if (t == 0) {
    const float invM = 1.0f / (float)(N_PTS * NSS);
    const float m0 = stats[0] * invM, m1 = stats[16] * invM, m2 = stats[32] * invM;
    const float cv00 = stats[48] * invM - m0 * m0, cv01 = stats[64] * invM - m0 * m1;
    const float cv02 = stats[80] * invM - m0 * m2, cv11 = stats[96] * invM - m1 * m1;
    const float cv12 = stats[112] * invM - m1 * m2, cv22 = stats[128] * invM - m2 * m2;
#pragma unroll
    for (int tt = 0; tt < 3; ++tt) {
      const float w0 = Wp1[0 * 3 + tt], w1 = Wp1[1 * 3 + tt], w2 = Wp1[2 * 3 + tt];
      const float mh = w0 * m0 + w1 * m1 + w2 * m2 + bp1[tt];
      const float var = w0 * w0 * cv00 + w1 * w1 * cv11 + w2 * w2 * cv22 +
                        2.f * (w0 * w1 * cv01 + w0 * w2 * cv02 + w1 * w2 * cv12);
      const float sc = gamma[tt] * rsqrtf(var + 1e-5f);
      ebn[tt] = w0 * sc; ebn[3 + tt] = w1 * sc; ebn[6 + tt] = w2 * sc;
      ebn[9 + tt] = (bp1[tt] - mh) * sc + beta[tt];
    }
  }
}

// ---------------- scatter: perm[sorted_pos] = original index ----------------
__global__ __launch_bounds__(256) void scatter_kernel(const float* __restrict__ p,
                                                      int* __restrict__ offs,
                                                      int* __restrict__ perm) {
  const int t = blockIdx.x * 256 + threadIdx.x;
  const int cidx = cell_of(p[t * 3 + 0], p[t * 3 + 1], p[t * 3 + 2]);
  const int pos = atomicAdd(&offs[cidx], 1);
  perm[pos] = t;
}

// ---------------- cross-lane helpers (reductions confined to lane bits 0..3) ----------------
template <int CTRL>
__device__ __forceinline__ float dppmv(float x) {
  return __int_as_float(__builtin_amdgcn_update_dpp(
      __float_as_int(x), __float_as_int(x), CTRL, 0xF, 0xF, true));
}
__device__ __forceinline__ float red16_add(float x) {
  x += dppmv<0xB1>(x);
  x += dppmv<0x4E>(x);
  x += __shfl_xor(x, 4, 64);
  x += __shfl_xor(x, 8, 64);
  return x;
}
__device__ __forceinline__ float red16_max(float x) {
  x = fmaxf(x, dppmv<0xB1>(x));
  x = fmaxf(x, dppmv<0x4E>(x));
  x = fmaxf(x, __shfl_xor(x, 4, 64));
  x = fmaxf(x, __shfl_xor(x, 8, 64));
  return x;
}

// ---------------- attention: 4 points per wave, 16 lanes each ----------------
__global__ __launch_bounds__(256, 4) void attn_kernel(
    const float* __restrict__ p, const int* __restrict__ idx,
    const unsigned short* __restrict__ kvq, const float* __restrict__ tq,
    const int* __restrict__ perm, const float* __restrict__ ebn,
    const float* __restrict__ Wp2, const float* __restrict__ bp2,
    float* __restrict__ out) {
  const int lane = threadIdx.x & 63;
  const int wave = threadIdx.x >> 6;
  const int b = blockIdx.x;
  const int sb = (b & 7) * 512 + (b >> 3);
  const int base = sb * 16 + wave * 4;
  const int quad = lane >> 4, lr = lane & 15;

  const int4 ng4 = *(const int4*)(perm + base);
  const int ng[4] = {ng4.x, ng4.y, ng4.z, ng4.w};
  const int nown = ng[quad];
  const int jall = idx[nown * NSS + lr];

  float S = 0.f;
#pragma unroll
  for (int g = 0; g < 4; ++g) {
    const int jg = __shfl(jall, (g << 4) | lr, 64);
    const short8 a0 = *(const short8*)(kvq + (size_t)ng[g] * 192 + quad * 8);
    const short8 a1 = *(const short8*)(kvq + (size_t)ng[g] * 192 + quad * 8 + 32);
    const short8 k0 = *(const short8*)(kvq + (size_t)jg * 192 + 64 + quad * 8);
    const short8 k1 = *(const short8*)(kvq + (size_t)jg * 192 + 64 + quad * 8 + 32);
    f32x4 acc = {0.f, 0.f, 0.f, 0.f};
    acc = __builtin_amdgcn_mfma_f32_16x16x32_bf16(a0, k0, acc, 0, 0, 0);
    acc = __builtin_amdgcn_mfma_f32_16x16x32_bf16(a1, k1, acc, 0, 0, 0);
    S = (quad == g) ? acc[0] : S;
  }

  float e[12];
#pragma unroll
  for (int i = 0; i < 12; ++i) e[i] = ebn[i];
  const float pnx = p[nown * 3 + 0], pny = p[nown * 3 + 1], pnz = p[nown * 3 + 2];
  const float dx = p[jall * 3 + 0] - pnx;
  const float dy = p[jall * 3 + 1] - pny;
  const float dz = p[jall * 3 + 2] - pnz;
  const float h0 = fmaxf(fmaf(dx, e[0], fmaf(dy, e[3], fmaf(dz, e[6], e[9]))), 0.f);
  const float h1 = fmaxf(fmaf(dx, e[1], fmaf(dy, e[4], fmaf(dz, e[7], e[10]))), 0.f);
  const float h2 = fmaxf(fmaf(dx, e[2], fmaf(dy, e[5], fmaf(dz, e[8], e[11]))), 0.f);

  const float4 t4 = ((const float4*)tq)[nown];
  const float a = (S + fmaf(h0, t4.x, fmaf(h1, t4.y, fmaf(h2, t4.z, t4.w)))) * 0.125f;

  const float mx = red16_max(a);
  const float ex = __expf(a - mx);
  const float den = red16_add(ex);
  const float w = ex / den;

  const float H0 = red16_add(w * h0);
  const float H1 = red16_add(w * h1);
  const float H2 = red16_add(w * h2);

  float o0 = 0.f, o1 = 0.f, o2 = 0.f, o3 = 0.f;
#pragma unroll
  for (int s = 0; s < NSS; ++s) {
    const int jr = __shfl(jall, (lane & 48) | s, 64);
    const float ws = __shfl(w, (lane & 48) | s, 64);
    const uint2 v2 = *(const uint2*)(kvq + (size_t)jr * 192 + 128 + lr * 4);
    o0 = fmaf(ws, bflo(v2.x), o0);
    o1 = fmaf(ws, bfhi(v2.x), o1);
    o2 = fmaf(ws, bflo(v2.y), o2);
    o3 = fmaf(ws, bfhi(v2.y), o3);
  }

  const float4 w20 = ((const float4*)Wp2)[0 * 16 + lr];
  const float4 w21 = ((const float4*)Wp2)[16 + lr];
  const float4 w22 = ((const float4*)Wp2)[32 + lr];
  const float4 b2 = ((const float4*)bp2)[lr];
  o0 += fmaf(H0, w20.x, fmaf(H1, w21.x, fmaf(H2, w22.x, b2.x)));
  o1 += fmaf(H0, w20.y, fmaf(H1, w21.y, fmaf(H2, w22.y, b2.y)));
  o2 += fmaf(H0, w20.z, fmaf(H1, w21.z, fmaf(H2, w22.z, b2.z)));
  o3 += fmaf(H0, w20.w, fmaf(H1, w21.w, fmaf(H2, w22.w, b2.w)));
  const float4 res = {o0, o1, o2, o3};
  ((float4*)out)[nown * 16 + lr] = res;
}

extern "C" void kernel_launch(void* const* d_in, const int* in_sizes, int n_in,
                              void* d_out, int out_size, void* d_ws, size_t ws_size,
                              hipStream_t stream) {
  const float* p     = (const float*)d_in[0];
  const float* x     = (const float*)d_in[1];
  const int*   idx   = (const int*)d_in[2];
  const float* Wq    = (const float*)d_in[3];
  const float* bq    = (const float*)d_in[4];
  const float* Wk    = (const float*)d_in[5];
  const float* bk    = (const float*)d_in[6];
  const float* Wv    = (const float*)d_in[7];
  const float* bv    = (const float*)d_in[8];
  const float* Wp1   = (const float*)d_in[9];
  const float* bp1   = (const float*)d_in[10];
  const float* gamma = (const float*)d_in[11];
  const float* beta  = (const float*)d_in[12];
  const float* Wp2   = (const float*)d_in[13];
  const float* bp2   = (const float*)d_in[14];
  float* out = (float*)d_out;

  char* w = (char*)d_ws;
  float* stats        = (float*)w;                      // 9 values, stride-16 padded (576 B)
  int* hist           = (int*)(w + 1024);               // 16384 B -> ends 17408
  float* tb           = (float*)(w + 17408);            // 16 B
  float* ebn          = (float*)(w + 17472);            // 48 B
  unsigned short* wt  = (unsigned short*)(w + 17536);   // 24576 B -> 42112
  unsigned short* wtq = (unsigned short*)(w + 42112);   // 2048 B -> 44160
  int* offs           = (int*)(w + 45056);              // 16384 B -> 61440
  int* perm           = (int*)(w + 65536);              // 262144 B -> 327680
  unsigned short* kvq = (unsigned short*)(w + 327680);  // 25165824 B
  float* tq           = (float*)(w + 25493504);         // 1048576 B

  hipMemsetAsync(w, 0, 17408, stream);  // stats zone + hist in one memset
  init_kernel<<<256, 256, 0, stream>>>(Wq, Wk, Wv, Wp2, bp2, bq, p, wt, wtq, tb, hist);
  stats_kernel<<<1024, 256, 0, stream>>>(p, idx, stats);
  qkv_gemm<<<N_PTS / 64, 256, 0, stream>>>(x, wt, wtq, tb, bq, bk, bv, kvq, tq);
  scan_kernel<<<1, 256, 0, stream>>>(hist, offs, stats, Wp1, bp1, gamma, beta, ebn);
  scatter_kernel<<<256, 256, 0, stream>>>(p, offs, perm);
  attn_kernel<<<N_PTS / 16, 256, 0, stream>>>(p, idx, kvq, tq, perm, ebn, Wp2, bp2, out);
}

// Round 7
// 188.784 us; speedup vs baseline: 1.0421x; 1.0421x over previous
//
#include <hip/hip_runtime.h>

#define N_PTS 65536
#define NSS 16
#define C 64

typedef __attribute__((ext_vector_type(8))) short short8;
typedef __attribute__((ext_vector_type(4))) float f32x4;

__device__ __forceinline__ unsigned short f2bf(float v) {
  unsigned int u = __float_as_uint(v);
  u += 0x7fffu + ((u >> 16) & 1u);  // RNE
  return (unsigned short)(u >> 16);
}
__device__ __forceinline__ float bflo(unsigned int u) { return __uint_as_float(u << 16); }
__device__ __forceinline__ float bfhi(unsigned int u) { return __uint_as_float(u & 0xffff0000u); }

// 16x16x16 morton cell id of a point (p in [0,10])
__device__ __forceinline__ int cell_of(float px, float py, float pz) {
  const int cx = min(15, max(0, (int)(px * 1.6f)));
  const int cy = min(15, max(0, (int)(py * 1.6f)));
  const int cz = min(15, max(0, (int)(pz * 1.6f)));
  int m = 0;
#pragma unroll
  for (int b = 0; b < 4; ++b)
    m |= (((cx >> b) & 1) << (3 * b + 2)) | (((cy >> b) & 1) << (3 * b + 1)) |
         (((cz >> b) & 1) << (3 * b));
  return m;
}

// ---------------- K1: x->bf16, wt/wtq/tb tables, hist, subsampled p_r moments ----------------
// grid = 1024 blocks x 256 (262144 threads)
__global__ __launch_bounds__(256) void init_kernel(
    const float* __restrict__ x,
    const float* __restrict__ Wq, const float* __restrict__ Wk, const float* __restrict__ Wv,
    const float* __restrict__ Wp2, const float* __restrict__ bp2, const float* __restrict__ bq,
    const float* __restrict__ p, const int* __restrict__ idx,
    unsigned short* __restrict__ xb, unsigned short* __restrict__ wt,
    unsigned short* __restrict__ wtq, float* __restrict__ tb,
    int* __restrict__ hist, float* __restrict__ stats) {
  const int t = blockIdx.x * 256 + threadIdx.x;

  // ---- xb: bf16 copy of x (coalesced, 4 float4 per thread) ----
  const float4* x4 = (const float4*)x;
  ushort4* xb4 = (ushort4*)xb;
#pragma unroll
  for (int j = 0; j < 4; ++j) {
    const int id = t + j * 262144;
    const float4 v = x4[id];
    ushort4 h4;
    h4.x = f2bf(v.x); h4.y = f2bf(v.y); h4.z = f2bf(v.z); h4.w = f2bf(v.w);
    xb4[id] = h4;
  }

  // ---- weight tables ----
  if (t < 192 * 64) {
    const int k = t / 192, ng = t % 192;
    const int mat = ng >> 6, n = ng & 63;
    const float* W = mat == 0 ? Wq : (mat == 1 ? Wk : Wv);
    wt[ng * 64 + k] = f2bf(W[k * 64 + n]);
  }
  if (t < 1024) {  // wtq[row][k] = sum_c Wq[k][c] * B2[row][c], rows 4..15 zero
    const int row = t >> 6, k = t & 63;
    float val = 0.f;
    if (row < 4) {
      const float* B2 = (row == 3) ? bp2 : (Wp2 + row * 64);
      for (int c2 = 0; c2 < 64; ++c2) val += Wq[k * 64 + c2] * B2[c2];
    }
    wtq[t] = f2bf(val);
  }
  if (t >= 1024 && t < 1028) {
    const int n2 = t - 1024;
    const float* B2 = (n2 == 3) ? bp2 : (Wp2 + n2 * 64);
    float val = 0.f;
    for (int c2 = 0; c2 < 64; ++c2) val += bq[c2] * B2[c2];
    tb[n2] = val;
  }

  // ---- hist for spatial sort ----
  if (t < N_PTS) {
    atomicAdd(&hist[cell_of(p[t * 3 + 0], p[t * 3 + 1], p[t * 3 + 2])], 1);
  }

  // ---- subsampled p_r moments: points n = 0,4,8,... all 16 neighbors ----
  const int n = (t >> 4) * 4;
  const int j = idx[n * NSS + (t & 15)];
  const float dx = p[j * 3 + 0] - p[n * 3 + 0];
  const float dy = p[j * 3 + 1] - p[n * 3 + 1];
  const float dz = p[j * 3 + 2] - p[n * 3 + 2];
  float s0 = dx, s1 = dy, s2 = dz;
  float s00 = dx * dx, s01 = dx * dy, s02 = dx * dz;
  float s11 = dy * dy, s12 = dy * dz, s22 = dz * dz;
#pragma unroll
  for (int m = 1; m < 64; m <<= 1) {
    s0 += __shfl_xor(s0, m, 64);  s1 += __shfl_xor(s1, m, 64);  s2 += __shfl_xor(s2, m, 64);
    s00 += __shfl_xor(s00, m, 64); s01 += __shfl_xor(s01, m, 64); s02 += __shfl_xor(s02, m, 64);
    s11 += __shfl_xor(s11, m, 64); s12 += __shfl_xor(s12, m, 64); s22 += __shfl_xor(s22, m, 64);
  }
  __shared__ float part[4][9];
  const int wave = threadIdx.x >> 6, lane = threadIdx.x & 63;
  if (lane == 0) {
    part[wave][0] = s0;  part[wave][1] = s1;  part[wave][2] = s2;
    part[wave][3] = s00; part[wave][4] = s01; part[wave][5] = s02;
    part[wave][6] = s11; part[wave][7] = s12; part[wave][8] = s22;
  }
  __syncthreads();
  if (threadIdx.x < 9) {
    const float acc = part[0][threadIdx.x] + part[1][threadIdx.x] +
                      part[2][threadIdx.x] + part[3][threadIdx.x];
    atomicAdd(&stats[threadIdx.x * 16], acc);
  }
}

// ---------------- K2: QKV MFMA GEMM (global A/B, one barrier) + scan/BN block ----------------
// blocks 0..1023: 64 points each; block 1024: scan + BN fold
__global__ __launch_bounds__(256) void qkv_gemm(
    const unsigned short* __restrict__ xb, const unsigned short* __restrict__ wt,
    const unsigned short* __restrict__ wtq, const float* __restrict__ tb,
    const float* __restrict__ bq, const float* __restrict__ bk, const float* __restrict__ bv,
    unsigned short* __restrict__ kvq, float* __restrict__ tq,
    const int* __restrict__ hist, int* __restrict__ offs,
    const float* __restrict__ stats,
    const float* __restrict__ Wp1, const float* __restrict__ bp1,
    const float* __restrict__ gamma, const float* __restrict__ beta,
    float* __restrict__ ebn) {
  __shared__ __align__(16) unsigned short kvs[64][192];

  if (blockIdx.x == 1024) {
    // ---- scan (parallel) over 4096 cell counts ----
    const int t = threadIdx.x;
    const int lane = t & 63, wv = t >> 6;
    int loc[16];
    int sum = 0;
#pragma unroll
    for (int i = 0; i < 16; ++i) { loc[i] = hist[t * 16 + i]; sum += loc[i]; }
    int incl = sum;
#pragma unroll
    for (int off = 1; off < 64; off <<= 1) {
      const int v = __shfl_up(incl, off, 64);
      if (lane >= off) incl += v;
    }
    __shared__ int wtot[4];
    if (lane == 63) wtot[wv] = incl;
    __syncthreads();
    int wbase = 0;
#pragma unroll
    for (int i = 0; i < 4; ++i) wbase += (i < wv) ? wtot[i] : 0;
    int run = wbase + incl - sum;  // exclusive prefix
#pragma unroll
    for (int i = 0; i < 16; ++i) { offs[t * 16 + i] = run; run += loc[i]; }

    if (t == 0) {
      const float invM = 1.0f / (float)(16384 * NSS);  // subsampled population
      const float m0 = stats[0] * invM, m1 = stats[16] * invM, m2 = stats[32] * invM;
      const float cv00 = stats[48] * invM - m0 * m0, cv01 = stats[64] * invM - m0 * m1;
      const float cv02 = stats[80] * invM - m0 * m2, cv11 = stats[96] * invM - m1 * m1;
      const float cv12 = stats[112] * invM - m1 * m2, cv22 = stats[128] * invM - m2 * m2;
#pragma unroll
      for (int tt = 0; tt < 3; ++tt) {
        const float w0 = Wp1[0 * 3 + tt], w1 = Wp1[1 * 3 + tt], w2 = Wp1[2 * 3 + tt];
        const float mh = w0 * m0 + w1 * m1 + w2 * m2 + bp1[tt];
        const float var = w0 * w0 * cv00 + w1 * w1 * cv11 + w2 * w2 * cv22 +
                          2.f * (w0 * w1 * cv01 + w0 * w2 * cv02 + w1 * w2 * cv12);
        const float sc = gamma[tt] * rsqrtf(var + 1e-5f);
        ebn[tt] = w0 * sc; ebn[3 + tt] = w1 * sc; ebn[6 + tt] = w2 * sc;
        ebn[9 + tt] = (bp1[tt] - mh) * sc + beta[tt];
      }
    }
    return;
  }

  const int t = threadIdx.x;
  const int p0 = blockIdx.x * 64;
  const int lane = t & 63, wave = t >> 6;
  const int quad = lane >> 4, lr = lane & 15;
  const int mrow = p0 + wave * 16 + lr;
  // A-frag straight from global bf16 x
  const short8 a0 = *(const short8*)(xb + (size_t)mrow * 64 + quad * 8);
  const short8 a1 = *(const short8*)(xb + (size_t)mrow * 64 + quad * 8 + 32);
#pragma unroll
  for (int nt = 0; nt < 12; ++nt) {
    const unsigned short* bpr = wt + (nt * 16 + lr) * 64 + quad * 8;
    const short8 b0 = *(const short8*)bpr;
    const short8 b1 = *(const short8*)(bpr + 32);
    f32x4 acc = {0.f, 0.f, 0.f, 0.f};
    acc = __builtin_amdgcn_mfma_f32_16x16x32_bf16(a0, b0, acc, 0, 0, 0);
    acc = __builtin_amdgcn_mfma_f32_16x16x32_bf16(a1, b1, acc, 0, 0, 0);
    const int mat = nt >> 2;
    const int c = (nt & 3) * 16 + lr;
    const float bias = (mat == 0 ? bq : (mat == 1 ? bk : bv))[c];
#pragma unroll
    for (int r = 0; r < 4; ++r) {
      const int row = wave * 16 + quad * 4 + r;
      kvs[row][mat * 64 + c] = f2bf(acc[r] + bias);
    }
  }
  {  // T = q . [Wp2 rows | bp2]
    const unsigned short* bpr = wtq + lr * 64 + quad * 8;
    const short8 b0 = *(const short8*)bpr;
    const short8 b1 = *(const short8*)(bpr + 32);
    f32x4 acc = {0.f, 0.f, 0.f, 0.f};
    acc = __builtin_amdgcn_mfma_f32_16x16x32_bf16(a0, b0, acc, 0, 0, 0);
    acc = __builtin_amdgcn_mfma_f32_16x16x32_bf16(a1, b1, acc, 0, 0, 0);
    if (lr < 4) {
      const float tbv = tb[lr];
#pragma unroll
      for (int r = 0; r < 4; ++r) {
        const int pt = p0 + wave * 16 + quad * 4 + r;
        tq[pt * 4 + lr] = acc[r] + tbv;
      }
    }
  }
  __syncthreads();
  // coalesced kvq store: 64 rows x 384 B contiguous = 1536 uint4
  const uint4* kvs4 = (const uint4*)&kvs[0][0];
  uint4* dst = (uint4*)(kvq + (size_t)p0 * 192);
#pragma unroll
  for (int j = 0; j < 6; ++j) dst[j * 256 + t] = kvs4[j * 256 + t];
}

// ---------------- K3: scatter: perm[sorted_pos] = original index ----------------
__global__ __launch_bounds__(256) void scatter_kernel(const float* __restrict__ p,
                                                      int* __restrict__ offs,
                                                      int* __restrict__ perm) {
  const int t = blockIdx.x * 256 + threadIdx.x;
  const int cidx = cell_of(p[t * 3 + 0], p[t * 3 + 1], p[t * 3 + 2]);
  const int pos = atomicAdd(&offs[cidx], 1);
  perm[pos] = t;
}

// ---------------- cross-lane helpers (reductions confined to lane bits 0..3) ----------------
template <int CTRL>
__device__ __forceinline__ float dppmv(float x) {
  return __int_as_float(__builtin_amdgcn_update_dpp(
      __float_as_int(x), __float_as_int(x), CTRL, 0xF, 0xF, true));
}
__device__ __forceinline__ float red16_add(float x) {
  x += dppmv<0xB1>(x);
  x += dppmv<0x4E>(x);
  x += __shfl_xor(x, 4, 64);
  x += __shfl_xor(x, 8, 64);
  return x;
}
__device__ __forceinline__ float red16_max(float x) {
  x = fmaxf(x, dppmv<0xB1>(x));
  x = fmaxf(x, dppmv<0x4E>(x));
  x = fmaxf(x, __shfl_xor(x, 4, 64));
  x = fmaxf(x, __shfl_xor(x, 8, 64));
  return x;
}

// ---------------- K4: attention: 4 points per wave, 16 lanes each ----------------
__global__ __launch_bounds__(256, 4) void attn_kernel(
    const float* __restrict__ p, const int* __restrict__ idx,
    const unsigned short* __restrict__ kvq, const float* __restrict__ tq,
    const int* __restrict__ perm, const float* __restrict__ ebn,
    const float* __restrict__ Wp2, const float* __restrict__ bp2,
    float* __restrict__ out) {
  const int lane = threadIdx.x & 63;
  const int wave = threadIdx.x >> 6;
  const int b = blockIdx.x;
  const int sb = (b & 7) * 512 + (b >> 3);
  const int base = sb * 16 + wave * 4;
  const int quad = lane >> 4, lr = lane & 15;

  const int4 ng4 = *(const int4*)(perm + base);
  const int ng[4] = {ng4.x, ng4.y, ng4.z, ng4.w};
  const int nown = ng[quad];
  const int jall = idx[nown * NSS + lr];

  float S = 0.f;
#pragma unroll
  for (int g = 0; g < 4; ++g) {
    const int jg = __shfl(jall, (g << 4) | lr, 64);
    const short8 a0 = *(const short8*)(kvq + (size_t)ng[g] * 192 + quad * 8);
    const short8 a1 = *(const short8*)(kvq + (size_t)ng[g] * 192 + quad * 8 + 32);
    const short8 k0 = *(const short8*)(kvq + (size_t)jg * 192 + 64 + quad * 8);
    const short8 k1 = *(const short8*)(kvq + (size_t)jg * 192 + 64 + quad * 8 + 32);
    f32x4 acc = {0.f, 0.f, 0.f, 0.f};
    acc = __builtin_amdgcn_mfma_f32_16x16x32_bf16(a0, k0, acc, 0, 0, 0);
    acc = __builtin_amdgcn_mfma_f32_16x16x32_bf16(a1, k1, acc, 0, 0, 0);
    S = (quad == g) ? acc[0] : S;
  }

  float e[12];
#pragma unroll
  for (int i = 0; i < 12; ++i) e[i] = ebn[i];
  const float pnx = p[nown * 3 + 0], pny = p[nown * 3 + 1], pnz = p[nown * 3 + 2];
  const float dx = p[jall * 3 + 0] - pnx;
  const float dy = p[jall * 3 + 1] - pny;
  const float dz = p[jall * 3 + 2] - pnz;
  const float h0 = fmaxf(fmaf(dx, e[0], fmaf(dy, e[3], fmaf(dz, e[6], e[9]))), 0.f);
  const float h1 = fmaxf(fmaf(dx, e[1], fmaf(dy, e[4], fmaf(dz, e[7], e[10]))), 0.f);
  const float h2 = fmaxf(fmaf(dx, e[2], fmaf(dy, e[5], fmaf(dz, e[8], e[11]))), 0.f);

  const float4 t4 = ((const float4*)tq)[nown];
  const float a = (S + fmaf(h0, t4.x, fmaf(h1, t4.y, fmaf(h2, t4.z, t4.w)))) * 0.125f;

  const float mx = red16_max(a);
  const float ex = __expf(a - mx);
  const float den = red16_add(ex);
  const float w = ex / den;

  const float H0 = red16_add(w * h0);
  const float H1 = red16_add(w * h1);
  const float H2 = red16_add(w * h2);

  float o0 = 0.f, o1 = 0.f, o2 = 0.f, o3 = 0.f;
#pragma unroll
  for (int s = 0; s < NSS; ++s) {
    const int jr = __shfl(jall, (lane & 48) | s, 64);
    const float ws = __shfl(w, (lane & 48) | s, 64);
    const uint2 v2 = *(const uint2*)(kvq + (size_t)jr * 192 + 128 + lr * 4);
    o0 = fmaf(ws, bflo(v2.x), o0);
    o1 = fmaf(ws, bfhi(v2.x), o1);
    o2 = fmaf(ws, bflo(v2.y), o2);
    o3 = fmaf(ws, bfhi(v2.y), o3);
  }

  const float4 w20 = ((const float4*)Wp2)[0 * 16 + lr];
  const float4 w21 = ((const float4*)Wp2)[16 + lr];
  const float4 w22 = ((const float4*)Wp2)[32 + lr];
  const float4 b2 = ((const float4*)bp2)[lr];
  o0 += fmaf(H0, w20.x, fmaf(H1, w21.x, fmaf(H2, w22.x, b2.x)));
  o1 += fmaf(H0, w20.y, fmaf(H1, w21.y, fmaf(H2, w22.y, b2.y)));
  o2 += fmaf(H0, w20.z, fmaf(H1, w21.z, fmaf(H2, w22.z, b2.z)));
  o3 += fmaf(H0, w20.w, fmaf(H1, w21.w, fmaf(H2, w22.w, b2.w)));
  const float4 res = {o0, o1, o2, o3};
  ((float4*)out)[nown * 16 + lr] = res;
}

extern "C" void kernel_launch(void* const* d_in, const int* in_sizes, int n_in,
                              void* d_out, int out_size, void* d_ws, size_t ws_size,
                              hipStream_t stream) {
  const float* p     = (const float*)d_in[0];
  const float* x     = (const float*)d_in[1];
  const int*   idx   = (const int*)d_in[2];
  const float* Wq    = (const float*)d_in[3];
  const float* bq    = (const float*)d_in[4];
  const float* Wk    = (const float*)d_in[5];
  const float* bk    = (const float*)d_in[6];
  const float* Wv    = (const float*)d_in[7];
  const float* bv    = (const float*)d_in[8];
  const float* Wp1   = (const float*)d_in[9];
  const float* bp1   = (const float*)d_in[10];
  const float* gamma = (const float*)d_in[11];
  const float* beta  = (const float*)d_in[12];
  const float* Wp2   = (const float*)d_in[13];
  const float* bp2   = (const float*)d_in[14];
  float* out = (float*)d_out;

  char* w = (char*)d_ws;
  float* stats        = (float*)w;                      // 9 values, stride-16 padded (576 B)
  int* hist           = (int*)(w + 1024);               // 16384 B -> ends 17408
  float* tb           = (float*)(w + 17408);            // 16 B
  float* ebn          = (float*)(w + 17472);            // 48 B
  unsigned short* wt  = (unsigned short*)(w + 17536);   // 24576 B -> 42112
  unsigned short* wtq = (unsigned short*)(w + 42112);   // 2048 B -> 44160
  int* offs           = (int*)(w + 45056);              // 16384 B -> 61440
  int* perm           = (int*)(w + 65536);              // 262144 B -> 327680
  unsigned short* kvq = (unsigned short*)(w + 327680);  // 25165824 B -> 25493504
  float* tq           = (float*)(w + 25493504);         // 1048576 B -> 26542080
  unsigned short* xb  = (unsigned short*)(w + 26542080);// 8388608 B

  hipMemsetAsync(w, 0, 17408, stream);  // stats zone + hist in one memset
  init_kernel<<<1024, 256, 0, stream>>>(x, Wq, Wk, Wv, Wp2, bp2, bq, p, idx,
                                        xb, wt, wtq, tb, hist, stats);
  qkv_gemm<<<1025, 256, 0, stream>>>(xb, wt, wtq, tb, bq, bk, bv, kvq, tq,
                                     hist, offs, stats, Wp1, bp1, gamma, beta, ebn);
  scatter_kernel<<<256, 256, 0, stream>>>(p, offs, perm);
  attn_kernel<<<N_PTS / 16, 256, 0, stream>>>(p, idx, kvq, tq, perm, ebn, Wp2, bp2, out);
}

// Round 8
// 157.640 us; speedup vs baseline: 1.2480x; 1.1976x over previous
//
#include <hip/hip_runtime.h>

#define N_PTS 65536
#define NSS 16
#define C 64

typedef __attribute__((ext_vector_type(8))) short short8;
typedef __attribute__((ext_vector_type(4))) float f32x4;

__device__ __forceinline__ unsigned short f2bf(float v) {
  unsigned int u = __float_as_uint(v);
  u += 0x7fffu + ((u >> 16) & 1u);  // RNE
  return (unsigned short)(u >> 16);
}
__device__ __forceinline__ unsigned int pk2(float lo, float hi) {
  return (unsigned int)f2bf(lo) | ((unsigned int)f2bf(hi) << 16);
}
__device__ __forceinline__ float bflo(unsigned int u) { return __uint_as_float(u << 16); }
__device__ __forceinline__ float bfhi(unsigned int u) { return __uint_as_float(u & 0xffff0000u); }

union BF8 { int4 i; short8 s; };

// ---------------- K1: weight tables + subsampled p_r moment partials (no atomics) ----------------
// grid = 256 blocks x 256. Thread t samples point t, neighbors (t&3)*4..+4.
__global__ __launch_bounds__(256) void init_kernel(
    const float* __restrict__ Wq, const float* __restrict__ Wk, const float* __restrict__ Wv,
    const float* __restrict__ Wp2, const float* __restrict__ bp2, const float* __restrict__ bq,
    const float* __restrict__ p, const int* __restrict__ idx,
    unsigned short* __restrict__ wt, unsigned short* __restrict__ wtq,
    float* __restrict__ tb, float* __restrict__ statsP) {
  const int t = blockIdx.x * 256 + threadIdx.x;

  // ---- weight tables ----
  if (t < 192 * 64) {
    const int k = t / 192, ng = t % 192;
    const int mat = ng >> 6, n = ng & 63;
    const float* W = mat == 0 ? Wq : (mat == 1 ? Wk : Wv);
    wt[ng * 64 + k] = f2bf(W[k * 64 + n]);
  }
  if (t < 1024) {  // wtq[row][k] = sum_c Wq[k][c] * B2[row][c], rows 4..15 zero
    const int row = t >> 6, k = t & 63;
    float val = 0.f;
    if (row < 4) {
      const float* B2 = (row == 3) ? bp2 : (Wp2 + row * 64);
      for (int c2 = 0; c2 < 64; ++c2) val += Wq[k * 64 + c2] * B2[c2];
    }
    wtq[t] = f2bf(val);
  }
  if (t >= 1024 && t < 1028) {
    const int n2 = t - 1024;
    const float* B2 = (n2 == 3) ? bp2 : (Wp2 + n2 * 64);
    float val = 0.f;
    for (int c2 = 0; c2 < 64; ++c2) val += bq[c2] * B2[c2];
    tb[n2] = val;
  }

  // ---- subsampled p_r moments: 262144 samples total ----
  const int n = t;
  const int4 j4 = ((const int4*)idx)[t * 4 + (t & 3)];
  const float pnx = p[n * 3 + 0], pny = p[n * 3 + 1], pnz = p[n * 3 + 2];
  const int js[4] = {j4.x, j4.y, j4.z, j4.w};
  float s0 = 0, s1 = 0, s2 = 0, s00 = 0, s01 = 0, s02 = 0, s11 = 0, s12 = 0, s22 = 0;
#pragma unroll
  for (int i = 0; i < 4; ++i) {
    const int j = js[i];
    const float dx = p[j * 3 + 0] - pnx;
    const float dy = p[j * 3 + 1] - pny;
    const float dz = p[j * 3 + 2] - pnz;
    s0 += dx; s1 += dy; s2 += dz;
    s00 += dx * dx; s01 += dx * dy; s02 += dx * dz;
    s11 += dy * dy; s12 += dy * dz; s22 += dz * dz;
  }
#pragma unroll
  for (int m = 1; m < 64; m <<= 1) {
    s0 += __shfl_xor(s0, m, 64);  s1 += __shfl_xor(s1, m, 64);  s2 += __shfl_xor(s2, m, 64);
    s00 += __shfl_xor(s00, m, 64); s01 += __shfl_xor(s01, m, 64); s02 += __shfl_xor(s02, m, 64);
    s11 += __shfl_xor(s11, m, 64); s12 += __shfl_xor(s12, m, 64); s22 += __shfl_xor(s22, m, 64);
  }
  __shared__ float part[4][9];
  const int wave = threadIdx.x >> 6, lane = threadIdx.x & 63;
  if (lane == 0) {
    part[wave][0] = s0;  part[wave][1] = s1;  part[wave][2] = s2;
    part[wave][3] = s00; part[wave][4] = s01; part[wave][5] = s02;
    part[wave][6] = s11; part[wave][7] = s12; part[wave][8] = s22;
  }
  __syncthreads();
  if (threadIdx.x < 9) {
    statsP[blockIdx.x * 12 + threadIdx.x] =
        part[0][threadIdx.x] + part[1][threadIdx.x] +
        part[2][threadIdx.x] + part[3][threadIdx.x];
  }
}

// ---------------- K2: QKV MFMA GEMM (fp32 x, in-reg bf16 pack) + stats-reduce/BN block ----------------
// blocks 0..1023: 64 points each; block 1024: reduce statsP + BN fold
__global__ __launch_bounds__(256) void qkv_gemm(
    const float* __restrict__ x, const unsigned short* __restrict__ wt,
    const unsigned short* __restrict__ wtq, const float* __restrict__ tb,
    const float* __restrict__ bq, const float* __restrict__ bk, const float* __restrict__ bv,
    unsigned short* __restrict__ kvq, float* __restrict__ tq,
    const float* __restrict__ statsP,
    const float* __restrict__ Wp1, const float* __restrict__ bp1,
    const float* __restrict__ gamma, const float* __restrict__ beta,
    float* __restrict__ ebn) {
  __shared__ __align__(16) unsigned short kvs[64][192];

  if (blockIdx.x == 1024) {
    // ---- reduce 256 block-partials, then BN fold ----
    const int t = threadIdx.x;
    float s[9];
#pragma unroll
    for (int c = 0; c < 9; ++c) s[c] = statsP[t * 12 + c];
#pragma unroll
    for (int m = 1; m < 64; m <<= 1) {
#pragma unroll
      for (int c = 0; c < 9; ++c) s[c] += __shfl_xor(s[c], m, 64);
    }
    __shared__ float part[4][9];
    __shared__ float tot[9];
    const int wave = t >> 6, lane = t & 63;
    if (lane == 0) {
#pragma unroll
      for (int c = 0; c < 9; ++c) part[wave][c] = s[c];
    }
    __syncthreads();
    if (t < 9) tot[t] = part[0][t] + part[1][t] + part[2][t] + part[3][t];
    __syncthreads();
    if (t == 0) {
      const float invM = 1.0f / 262144.0f;
      const float m0 = tot[0] * invM, m1 = tot[1] * invM, m2 = tot[2] * invM;
      const float cv00 = tot[3] * invM - m0 * m0, cv01 = tot[4] * invM - m0 * m1;
      const float cv02 = tot[5] * invM - m0 * m2, cv11 = tot[6] * invM - m1 * m1;
      const float cv12 = tot[7] * invM - m1 * m2, cv22 = tot[8] * invM - m2 * m2;
#pragma unroll
      for (int tt = 0; tt < 3; ++tt) {
        const float w0 = Wp1[0 * 3 + tt], w1 = Wp1[1 * 3 + tt], w2 = Wp1[2 * 3 + tt];
        const float mh = w0 * m0 + w1 * m1 + w2 * m2 + bp1[tt];
        const float var = w0 * w0 * cv00 + w1 * w1 * cv11 + w2 * w2 * cv22 +
                          2.f * (w0 * w1 * cv01 + w0 * w2 * cv02 + w1 * w2 * cv12);
        const float sc = gamma[tt] * rsqrtf(var + 1e-5f);
        ebn[tt] = w0 * sc; ebn[3 + tt] = w1 * sc; ebn[6 + tt] = w2 * sc;
        ebn[9 + tt] = (bp1[tt] - mh) * sc + beta[tt];
      }
    }
    return;
  }

  const int t = threadIdx.x;
  const int p0 = blockIdx.x * 64;
  const int lane = t & 63, wave = t >> 6;
  const int quad = lane >> 4, lr = lane & 15;
  const int mrow = p0 + wave * 16 + lr;
  // A-frag: load fp32 x row, pack to bf16 in-register
  const float* xrow = x + (size_t)mrow * 64;
  const float4 fa = *(const float4*)(xrow + quad * 8);
  const float4 fb = *(const float4*)(xrow + quad * 8 + 4);
  const float4 fc = *(const float4*)(xrow + 32 + quad * 8);
  const float4 fd = *(const float4*)(xrow + 32 + quad * 8 + 4);
  BF8 ua, ub;
  ua.i = make_int4(pk2(fa.x, fa.y), pk2(fa.z, fa.w), pk2(fb.x, fb.y), pk2(fb.z, fb.w));
  ub.i = make_int4(pk2(fc.x, fc.y), pk2(fc.z, fc.w), pk2(fd.x, fd.y), pk2(fd.z, fd.w));
  const short8 a0 = ua.s;
  const short8 a1 = ub.s;
#pragma unroll
  for (int nt = 0; nt < 12; ++nt) {
    const unsigned short* bpr = wt + (nt * 16 + lr) * 64 + quad * 8;
    const short8 b0 = *(const short8*)bpr;
    const short8 b1 = *(const short8*)(bpr + 32);
    f32x4 acc = {0.f, 0.f, 0.f, 0.f};
    acc = __builtin_amdgcn_mfma_f32_16x16x32_bf16(a0, b0, acc, 0, 0, 0);
    acc = __builtin_amdgcn_mfma_f32_16x16x32_bf16(a1, b1, acc, 0, 0, 0);
    const int mat = nt >> 2;
    const int c = (nt & 3) * 16 + lr;
    const float bias = (mat == 0 ? bq : (mat == 1 ? bk : bv))[c];
#pragma unroll
    for (int r = 0; r < 4; ++r) {
      const int row = wave * 16 + quad * 4 + r;
      kvs[row][mat * 64 + c] = f2bf(acc[r] + bias);
    }
  }
  {  // T = q . [Wp2 rows | bp2]
    const unsigned short* bpr = wtq + lr * 64 + quad * 8;
    const short8 b0 = *(const short8*)bpr;
    const short8 b1 = *(const short8*)(bpr + 32);
    f32x4 acc = {0.f, 0.f, 0.f, 0.f};
    acc = __builtin_amdgcn_mfma_f32_16x16x32_bf16(a0, b0, acc, 0, 0, 0);
    acc = __builtin_amdgcn_mfma_f32_16x16x32_bf16(a1, b1, acc, 0, 0, 0);
    if (lr < 4) {
      const float tbv = tb[lr];
#pragma unroll
      for (int r = 0; r < 4; ++r) {
        const int pt = p0 + wave * 16 + quad * 4 + r;
        tq[pt * 4 + lr] = acc[r] + tbv;
      }
    }
  }
  __syncthreads();
  // coalesced kvq store: 64 rows x 384 B contiguous = 1536 uint4
  const uint4* kvs4 = (const uint4*)&kvs[0][0];
  uint4* dst = (uint4*)(kvq + (size_t)p0 * 192);
#pragma unroll
  for (int j = 0; j < 6; ++j) dst[j * 256 + t] = kvs4[j * 256 + t];
}

// ---------------- cross-lane helpers (reductions confined to lane bits 0..3) ----------------
template <int CTRL>
__device__ __forceinline__ float dppmv(float x) {
  return __int_as_float(__builtin_amdgcn_update_dpp(
      __float_as_int(x), __float_as_int(x), CTRL, 0xF, 0xF, true));
}
__device__ __forceinline__ float red16_add(float x) {
  x += dppmv<0xB1>(x);
  x += dppmv<0x4E>(x);
  x += __shfl_xor(x, 4, 64);
  x += __shfl_xor(x, 8, 64);
  return x;
}
__device__ __forceinline__ float red16_max(float x) {
  x = fmaxf(x, dppmv<0xB1>(x));
  x = fmaxf(x, dppmv<0x4E>(x));
  x = fmaxf(x, __shfl_xor(x, 4, 64));
  x = fmaxf(x, __shfl_xor(x, 8, 64));
  return x;
}

// ---------------- K3: attention: 4 consecutive points per wave, 16 lanes each ----------------
__global__ __launch_bounds__(256, 4) void attn_kernel(
    const float* __restrict__ p, const int* __restrict__ idx,
    const unsigned short* __restrict__ kvq, const float* __restrict__ tq,
    const float* __restrict__ ebn,
    const float* __restrict__ Wp2, const float* __restrict__ bp2,
    float* __restrict__ out) {
  const int lane = threadIdx.x & 63;
  const int wave = threadIdx.x >> 6;
  const int base = blockIdx.x * 16 + wave * 4;
  const int quad = lane >> 4, lr = lane & 15;

  const int nown = base + quad;
  const int jall = idx[nown * NSS + lr];

  float S = 0.f;
#pragma unroll
  for (int g = 0; g < 4; ++g) {
    const int jg = __shfl(jall, (g << 4) | lr, 64);
    const short8 a0 = *(const short8*)(kvq + (size_t)(base + g) * 192 + quad * 8);
    const short8 a1 = *(const short8*)(kvq + (size_t)(base + g) * 192 + quad * 8 + 32);
    const short8 k0 = *(const short8*)(kvq + (size_t)jg * 192 + 64 + quad * 8);
    const short8 k1 = *(const short8*)(kvq + (size_t)jg * 192 + 64 + quad * 8 + 32);
    f32x4 acc = {0.f, 0.f, 0.f, 0.f};
    acc = __builtin_amdgcn_mfma_f32_16x16x32_bf16(a0, k0, acc, 0, 0, 0);
    acc = __builtin_amdgcn_mfma_f32_16x16x32_bf16(a1, k1, acc, 0, 0, 0);
    S = (quad == g) ? acc[0] : S;
  }

  float e[12];
#pragma unroll
  for (int i = 0; i < 12; ++i) e[i] = ebn[i];
  const float pnx = p[nown * 3 + 0], pny = p[nown * 3 + 1], pnz = p[nown * 3 + 2];
  const float dx = p[jall * 3 + 0] - pnx;
  const float dy = p[jall * 3 + 1] - pny;
  const float dz = p[jall * 3 + 2] - pnz;
  const float h0 = fmaxf(fmaf(dx, e[0], fmaf(dy, e[3], fmaf(dz, e[6], e[9]))), 0.f);
  const float h1 = fmaxf(fmaf(dx, e[1], fmaf(dy, e[4], fmaf(dz, e[7], e[10]))), 0.f);
  const float h2 = fmaxf(fmaf(dx, e[2], fmaf(dy, e[5], fmaf(dz, e[8], e[11]))), 0.f);

  const float4 t4 = ((const float4*)tq)[nown];
  const float a = (S + fmaf(h0, t4.x, fmaf(h1, t4.y, fmaf(h2, t4.z, t4.w)))) * 0.125f;

  const float mx = red16_max(a);
  const float ex = __expf(a - mx);
  const float den = red16_add(ex);
  const float w = ex / den;

  const float H0 = red16_add(w * h0);
  const float H1 = red16_add(w * h1);
  const float H2 = red16_add(w * h2);

  float o0 = 0.f, o1 = 0.f, o2 = 0.f, o3 = 0.f;
#pragma unroll
  for (int s = 0; s < NSS; ++s) {
    const int jr = __shfl(jall, (lane & 48) | s, 64);
    const float ws = __shfl(w, (lane & 48) | s, 64);
    const uint2 v2 = *(const uint2*)(kvq + (size_t)jr * 192 + 128 + lr * 4);
    o0 = fmaf(ws, bflo(v2.x), o0);
    o1 = fmaf(ws, bfhi(v2.x), o1);
    o2 = fmaf(ws, bflo(v2.y), o2);
    o3 = fmaf(ws, bfhi(v2.y), o3);
  }

  const float4 w20 = ((const float4*)Wp2)[0 * 16 + lr];
  const float4 w21 = ((const float4*)Wp2)[16 + lr];
  const float4 w22 = ((const float4*)Wp2)[32 + lr];
  const float4 b2 = ((const float4*)bp2)[lr];
  o0 += fmaf(H0, w20.x, fmaf(H1, w21.x, fmaf(H2, w22.x, b2.x)));
  o1 += fmaf(H0, w20.y, fmaf(H1, w21.y, fmaf(H2, w22.y, b2.y)));
  o2 += fmaf(H0, w20.z, fmaf(H1, w21.z, fmaf(H2, w22.z, b2.z)));
  o3 += fmaf(H0, w20.w, fmaf(H1, w21.w, fmaf(H2, w22.w, b2.w)));
  const float4 res = {o0, o1, o2, o3};
  ((float4*)out)[nown * 16 + lr] = res;
}

extern "C" void kernel_launch(void* const* d_in, const int* in_sizes, int n_in,
                              void* d_out, int out_size, void* d_ws, size_t ws_size,
                              hipStream_t stream) {
  const float* p     = (const float*)d_in[0];
  const float* x     = (const float*)d_in[1];
  const int*   idx   = (const int*)d_in[2];
  const float* Wq    = (const float*)d_in[3];
  const float* bq    = (const float*)d_in[4];
  const float* Wk    = (const float*)d_in[5];
  const float* bk    = (const float*)d_in[6];
  const float* Wv    = (const float*)d_in[7];
  const float* bv    = (const float*)d_in[8];
  const float* Wp1   = (const float*)d_in[9];
  const float* bp1   = (const float*)d_in[10];
  const float* gamma = (const float*)d_in[11];
  const float* beta  = (const float*)d_in[12];
  const float* Wp2   = (const float*)d_in[13];
  const float* bp2   = (const float*)d_in[14];
  float* out = (float*)d_out;

  char* w = (char*)d_ws;
  float* statsP       = (float*)w;                      // 256*12 floats = 12288 B
  float* tb           = (float*)(w + 12544);            // 16 B
  float* ebn          = (float*)(w + 12608);            // 48 B
  unsigned short* wt  = (unsigned short*)(w + 16384);   // 24576 B -> 40960
  unsigned short* wtq = (unsigned short*)(w + 40960);   // 2048 B -> 43008
  unsigned short* kvq = (unsigned short*)(w + 65536);   // 25165824 B -> 25231360
  float* tq           = (float*)(w + 25231360);         // 1048576 B

  init_kernel<<<256, 256, 0, stream>>>(Wq, Wk, Wv, Wp2, bp2, bq, p, idx, wt, wtq, tb, statsP);
  qkv_gemm<<<1025, 256, 0, stream>>>(x, wt, wtq, tb, bq, bk, bv, kvq, tq,
                                     statsP, Wp1, bp1, gamma, beta, ebn);
  attn_kernel<<<N_PTS / 16, 256, 0, stream>>>(p, idx, kvq, tq, ebn, Wp2, bp2, out);
}

// Round 10
// 155.397 us; speedup vs baseline: 1.2660x; 1.0144x over previous
//
#include <hip/hip_runtime.h>

#define N_PTS 65536
#define NSS 16

typedef __attribute__((ext_vector_type(8))) short short8;
typedef __attribute__((ext_vector_type(4))) float f32x4;

__device__ __forceinline__ unsigned short f2bf(float v) {
  unsigned int u = __float_as_uint(v);
  u += 0x7fffu + ((u >> 16) & 1u);  // RNE
  return (unsigned short)(u >> 16);
}
__device__ __forceinline__ unsigned int pk2(float lo, float hi) {
  return (unsigned int)f2bf(lo) | ((unsigned int)f2bf(hi) << 16);
}
__device__ __forceinline__ float bflo(unsigned int u) { return __uint_as_float(u << 16); }
__device__ __forceinline__ float bfhi(unsigned int u) { return __uint_as_float(u & 0xffff0000u); }

union BF8 { int4 i; short8 s; };
union BU  { ushort4 u[2]; short8 s; };

// ================= K1: self-contained QKV GEMM + T-MFMA + stats partials =================
// 1024 blocks x 256. LDS: wt 26112 + kvs 24576 + b2 640 = 51.3 KB -> 3 blocks/CU.
__global__ __launch_bounds__(256, 3) void qkv_kernel(
    const float* __restrict__ x,
    const float* __restrict__ Wq, const float* __restrict__ Wk, const float* __restrict__ Wv,
    const float* __restrict__ bq, const float* __restrict__ bk, const float* __restrict__ bv,
    const float* __restrict__ Wp2, const float* __restrict__ bp2,
    const float* __restrict__ p, const int* __restrict__ idx,
    unsigned short* __restrict__ kvq, float* __restrict__ tq, float* __restrict__ statsP) {
  __shared__ __align__(16) unsigned short wtl[192 * 68];  // [ng][k], pitch 68 (b64-aligned)
  __shared__ __align__(16) unsigned short kvs[64 * 192];  // [row][Q|K|V]
  __shared__ __align__(16) unsigned short b2s[5 * 64];    // rows 0-3 = Wp2|bp2, row 4 = zeros
  const int t = threadIdx.x, blk = blockIdx.x;
  const int p0 = blk * 64;
  const int lane = t & 63, wave = t >> 6;
  const int quad = lane >> 4, lr = lane & 15;

  // ---- stats sample (issue gathers early; consumed late) ----
  const int pn = p0 + (t >> 2);
  const int4 j4 = ((const int4*)idx)[pn * 4 + (t & 3)];
  const float pnx = p[pn * 3 + 0], pny = p[pn * 3 + 1], pnz = p[pn * 3 + 2];
  const int js[4] = {j4.x, j4.y, j4.z, j4.w};
  float jx[4], jy[4], jz[4];
#pragma unroll
  for (int i = 0; i < 4; ++i) {
    jx[i] = p[js[i] * 3 + 0]; jy[i] = p[js[i] * 3 + 1]; jz[i] = p[js[i] * 3 + 2];
  }

  // ---- build transposed bf16 weight table in LDS ----
#pragma unroll 8
  for (int i = 0; i < 48; ++i) {
    const int id = i * 256 + t;
    const int mat = id >> 12, rem = id & 4095;
    const int k = rem >> 6, n = rem & 63;
    const float* W = mat == 0 ? Wq : (mat == 1 ? Wk : Wv);
    wtl[(mat * 64 + n) * 68 + k] = f2bf(W[k * 64 + n]);
  }
  // ---- B2 table: rows 0-2 = Wp2, row 3 = bp2, row 4 = zeros ----
  {
    const int row = t >> 6, c = t & 63;
    b2s[t] = f2bf(row < 3 ? Wp2[row * 64 + c] : bp2[c]);
    if (t < 64) b2s[256 + t] = 0;
  }
  __syncthreads();

  // ---- A-fragment: fp32 x row -> bf16 in-register ----
  const int mrow = p0 + wave * 16 + lr;
  const float* xrow = x + (size_t)mrow * 64;
  const float4 fa = *(const float4*)(xrow + quad * 8);
  const float4 fb = *(const float4*)(xrow + quad * 8 + 4);
  const float4 fc = *(const float4*)(xrow + 32 + quad * 8);
  const float4 fd = *(const float4*)(xrow + 32 + quad * 8 + 4);
  BF8 ua, ub;
  ua.i = make_int4(pk2(fa.x, fa.y), pk2(fa.z, fa.w), pk2(fb.x, fb.y), pk2(fb.z, fb.w));
  ub.i = make_int4(pk2(fc.x, fc.y), pk2(fc.z, fc.w), pk2(fd.x, fd.y), pk2(fd.z, fd.w));
  const short8 a0 = ua.s;
  const short8 a1 = ub.s;

  // ---- 12 MFMA tiles: Q|K|V ----
#pragma unroll
  for (int nt = 0; nt < 12; ++nt) {
    const unsigned short* bpr = wtl + (nt * 16 + lr) * 68 + quad * 8;
    BU B0, B1;
    B0.u[0] = *(const ushort4*)bpr;        B0.u[1] = *(const ushort4*)(bpr + 4);
    B1.u[0] = *(const ushort4*)(bpr + 32); B1.u[1] = *(const ushort4*)(bpr + 36);
    f32x4 acc = {0.f, 0.f, 0.f, 0.f};
    acc = __builtin_amdgcn_mfma_f32_16x16x32_bf16(a0, B0.s, acc, 0, 0, 0);
    acc = __builtin_amdgcn_mfma_f32_16x16x32_bf16(a1, B1.s, acc, 0, 0, 0);
    const int mat = nt >> 2;
    const int c = (nt & 3) * 16 + lr;
    const float bias = (mat == 0 ? bq : (mat == 1 ? bk : bv))[c];
#pragma unroll
    for (int r = 0; r < 4; ++r) {
      const int row = wave * 16 + quad * 4 + r;
      kvs[row * 192 + mat * 64 + c] = f2bf(acc[r] + bias);
    }
  }
  // ---- T-MFMA: T = Q . [Wp2 rows | bp2] (Q read back from kvs, same-wave rows) ----
  {
    const unsigned short* qp = kvs + (wave * 16 + lr) * 192;
    const short8 a0q = *(const short8*)(qp + quad * 8);
    const short8 a1q = *(const short8*)(qp + quad * 8 + 32);
    const unsigned short* b2p = b2s + (lr < 4 ? lr : 4) * 64 + quad * 8;
    const short8 b0q = *(const short8*)b2p;
    const short8 b1q = *(const short8*)(b2p + 32);
    f32x4 acc = {0.f, 0.f, 0.f, 0.f};
    acc = __builtin_amdgcn_mfma_f32_16x16x32_bf16(a0q, b0q, acc, 0, 0, 0);
    acc = __builtin_amdgcn_mfma_f32_16x16x32_bf16(a1q, b1q, acc, 0, 0, 0);
    if (lr < 4) {
#pragma unroll
      for (int r = 0; r < 4; ++r) {
        const int pt = p0 + wave * 16 + quad * 4 + r;
        tq[pt * 4 + lr] = acc[r];
      }
    }
  }

  // ---- stats moments + wave reduce (registers only, pre-barrier) ----
  float s0 = 0, s1 = 0, s2 = 0, s00 = 0, s01 = 0, s02 = 0, s11 = 0, s12 = 0, s22 = 0;
#pragma unroll
  for (int i = 0; i < 4; ++i) {
    const float dx = jx[i] - pnx, dy = jy[i] - pny, dz = jz[i] - pnz;
    s0 += dx; s1 += dy; s2 += dz;
    s00 += dx * dx; s01 += dx * dy; s02 += dx * dz;
    s11 += dy * dy; s12 += dy * dz; s22 += dz * dz;
  }
#pragma unroll
  for (int m = 1; m < 64; m <<= 1) {
    s0 += __shfl_xor(s0, m, 64);  s1 += __shfl_xor(s1, m, 64);  s2 += __shfl_xor(s2, m, 64);
    s00 += __shfl_xor(s00, m, 64); s01 += __shfl_xor(s01, m, 64); s02 += __shfl_xor(s02, m, 64);
    s11 += __shfl_xor(s11, m, 64); s12 += __shfl_xor(s12, m, 64); s22 += __shfl_xor(s22, m, 64);
  }

  __syncthreads();  // kvs complete; b2s free for reuse

  // ---- coalesced kvq store ----
  const uint4* kvs4 = (const uint4*)kvs;
  uint4* dst = (uint4*)(kvq + (size_t)p0 * 192);
#pragma unroll
  for (int j = 0; j < 6; ++j) dst[j * 256 + t] = kvs4[j * 256 + t];

  // ---- stats partials out (no atomics): statsP[c][blk] ----
  float* part = (float*)b2s;  // reuse (144 B)
  if (lane == 0) {
    part[wave * 9 + 0] = s0;  part[wave * 9 + 1] = s1;  part[wave * 9 + 2] = s2;
    part[wave * 9 + 3] = s00; part[wave * 9 + 4] = s01; part[wave * 9 + 5] = s02;
    part[wave * 9 + 6] = s11; part[wave * 9 + 7] = s12; part[wave * 9 + 8] = s22;
  }
  __syncthreads();
  if (t < 9) {
    statsP[t * 1024 + blk] = part[t] + part[9 + t] + part[18 + t] + part[27 + t];
  }
}

// ---------------- cross-lane helpers (reductions confined to lane bits 0..3) ----------------
template <int CTRL>
__device__ __forceinline__ float dppmv(float x) {
  return __int_as_float(__builtin_amdgcn_update_dpp(
      __float_as_int(x), __float_as_int(x), CTRL, 0xF, 0xF, true));
}
__device__ __forceinline__ float red16_add(float x) {
  x += dppmv<0xB1>(x);
  x += dppmv<0x4E>(x);
  x += __shfl_xor(x, 4, 64);
  x += __shfl_xor(x, 8, 64);
  return x;
}
__device__ __forceinline__ float red16_max(float x) {
  x = fmaxf(x, dppmv<0xB1>(x));
  x = fmaxf(x, dppmv<0x4E>(x));
  x = fmaxf(x, __shfl_xor(x, 4, 64));
  x = fmaxf(x, __shfl_xor(x, 8, 64));
  return x;
}

// ================= K2: per-block BN fold + attention =================
// 1024 blocks x 256; each wave: 4 iters x 4 points.
__global__ __launch_bounds__(256, 4) void attn_kernel(
    const float* __restrict__ p, const int* __restrict__ idx,
    const unsigned short* __restrict__ kvq, const float* __restrict__ tq,
    const float* __restrict__ statsP,
    const float* __restrict__ Wp1, const float* __restrict__ bp1,
    const float* __restrict__ gamma, const float* __restrict__ beta,
    const float* __restrict__ Wp2, const float* __restrict__ bp2,
    float* __restrict__ out) {
  __shared__ float red[4][9];
  __shared__ float ebn_s[12];
  const int t = threadIdx.x, blk = blockIdx.x;
  const int lane = t & 63, wave = t >> 6;
  const int quad = lane >> 4, lr = lane & 15;

  // ---- reduce 1024 stats partials (coalesced) + BN fold ----
  {
    float s[9];
#pragma unroll
    for (int c = 0; c < 9; ++c) s[c] = 0.f;
#pragma unroll
    for (int i = 0; i < 4; ++i) {
      const int bI = i * 256 + t;
#pragma unroll
      for (int c = 0; c < 9; ++c) s[c] += statsP[c * 1024 + bI];
    }
#pragma unroll
    for (int m = 1; m < 64; m <<= 1) {
#pragma unroll
      for (int c = 0; c < 9; ++c) s[c] += __shfl_xor(s[c], m, 64);
    }
    if (lane == 0) {
#pragma unroll
      for (int c = 0; c < 9; ++c) red[wave][c] = s[c];
    }
    __syncthreads();
    if (t == 0) {
      float tot[9];
#pragma unroll
      for (int c = 0; c < 9; ++c) tot[c] = red[0][c] + red[1][c] + red[2][c] + red[3][c];
      const float invM = 1.0f / 1048576.0f;
      const float m0 = tot[0] * invM, m1 = tot[1] * invM, m2 = tot[2] * invM;
      const float cv00 = tot[3] * invM - m0 * m0, cv01 = tot[4] * invM - m0 * m1;
      const float cv02 = tot[5] * invM - m0 * m2, cv11 = tot[6] * invM - m1 * m1;
      const float cv12 = tot[7] * invM - m1 * m2, cv22 = tot[8] * invM - m2 * m2;
#pragma unroll
      for (int tt = 0; tt < 3; ++tt) {
        const float w0 = Wp1[0 * 3 + tt], w1 = Wp1[1 * 3 + tt], w2 = Wp1[2 * 3 + tt];
        const float mh = w0 * m0 + w1 * m1 + w2 * m2 + bp1[tt];
        const float var = w0 * w0 * cv00 + w1 * w1 * cv11 + w2 * w2 * cv22 +
                          2.f * (w0 * w1 * cv01 + w0 * w2 * cv02 + w1 * w2 * cv12);
        const float sc = gamma[tt] * rsqrtf(var + 1e-5f);
        ebn_s[tt] = w0 * sc; ebn_s[3 + tt] = w1 * sc; ebn_s[6 + tt] = w2 * sc;
        ebn_s[9 + tt] = (bp1[tt] - mh) * sc + beta[tt];
      }
    }
    __syncthreads();
  }

  float e[12];
#pragma unroll
  for (int i = 0; i < 12; ++i) e[i] = ebn_s[i];
  const float4 w20 = ((const float4*)Wp2)[lr];
  const float4 w21 = ((const float4*)Wp2)[16 + lr];
  const float4 w22 = ((const float4*)Wp2)[32 + lr];
  const float4 b2v = ((const float4*)bp2)[lr];

#pragma unroll 1
  for (int it = 0; it < 4; ++it) {
    const int base = blk * 64 + wave * 16 + it * 4;
    const int nown = base + quad;

    // neighbor ids: direct broadcast loads
    const int jg0 = idx[(base + 0) * NSS + lr];
    const int jg1 = idx[(base + 1) * NSS + lr];
    const int jg2 = idx[(base + 2) * NSS + lr];
    const int jg3 = idx[(base + 3) * NSS + lr];
    const int jall = quad == 0 ? jg0 : (quad == 1 ? jg1 : (quad == 2 ? jg2 : jg3));

    // hoisted V gathers: own point's 16 neighbors, channels 4lr..4lr+3
    uint2 v[16];
    {
      const int4* idxr = (const int4*)(idx + (size_t)nown * NSS);
      const int4 ja = idxr[0], jb = idxr[1], jc = idxr[2], jd = idxr[3];
      const int jns[16] = {ja.x, ja.y, ja.z, ja.w, jb.x, jb.y, jb.z, jb.w,
                           jc.x, jc.y, jc.z, jc.w, jd.x, jd.y, jd.z, jd.w};
#pragma unroll
      for (int s = 0; s < NSS; ++s)
        v[s] = *(const uint2*)(kvq + (size_t)jns[s] * 192 + 128 + lr * 4);
    }

    const float pnx = p[nown * 3 + 0], pny = p[nown * 3 + 1], pnz = p[nown * 3 + 2];
    const float dx = p[jall * 3 + 0] - pnx;
    const float dy = p[jall * 3 + 1] - pny;
    const float dz = p[jall * 3 + 2] - pnz;
    const float4 t4 = ((const float4*)tq)[nown];

    // scores via MFMA: one pair per point-group; lane keeps its own group's score
    float S = 0.f;
#pragma unroll
    for (int g = 0; g < 4; ++g) {
      const int jg = g == 0 ? jg0 : (g == 1 ? jg1 : (g == 2 ? jg2 : jg3));
      const short8 a0 = *(const short8*)(kvq + (size_t)(base + g) * 192 + quad * 8);
      const short8 a1 = *(const short8*)(kvq + (size_t)(base + g) * 192 + quad * 8 + 32);
      const short8 k0 = *(const short8*)(kvq + (size_t)jg * 192 + 64 + quad * 8);
      const short8 k1 = *(const short8*)(kvq + (size_t)jg * 192 + 64 + quad * 8 + 32);
      f32x4 acc = {0.f, 0.f, 0.f, 0.f};
      acc = __builtin_amdgcn_mfma_f32_16x16x32_bf16(a0, k0, acc, 0, 0, 0);
      acc = __builtin_amdgcn_mfma_f32_16x16x32_bf16(a1, k1, acc, 0, 0, 0);
      S = (quad == g) ? acc[0] : S;
    }

    const float h0 = fmaxf(fmaf(dx, e[0], fmaf(dy, e[3], fmaf(dz, e[6], e[9]))), 0.f);
    const float h1 = fmaxf(fmaf(dx, e[1], fmaf(dy, e[4], fmaf(dz, e[7], e[10]))), 0.f);
    const float h2 = fmaxf(fmaf(dx, e[2], fmaf(dy, e[5], fmaf(dz, e[8], e[11]))), 0.f);

    const float a = (S + fmaf(h0, t4.x, fmaf(h1, t4.y, fmaf(h2, t4.z, t4.w)))) * 0.125f;
    const float mx = red16_max(a);
    const float ex = __expf(a - mx);
    const float den = red16_add(ex);
    const float w = ex / den;

    const float H0 = red16_add(w * h0);
    const float H1 = red16_add(w * h1);
    const float H2 = red16_add(w * h2);

    // V accumulate with pre-loaded rows
    float o0 = 0.f, o1 = 0.f, o2 = 0.f, o3 = 0.f;
#pragma unroll
    for (int s = 0; s < NSS; ++s) {
      const float ws = __shfl(w, (lane & 48) | s, 64);
      o0 = fmaf(ws, bflo(v[s].x), o0);
      o1 = fmaf(ws, bfhi(v[s].x), o1);
      o2 = fmaf(ws, bflo(v[s].y), o2);
      o3 = fmaf(ws, bfhi(v[s].y), o3);
    }

    o0 += fmaf(H0, w20.x, fmaf(H1, w21.x, fmaf(H2, w22.x, b2v.x)));
    o1 += fmaf(H0, w20.y, fmaf(H1, w21.y, fmaf(H2, w22.y, b2v.y)));
    o2 += fmaf(H0, w20.z, fmaf(H1, w21.z, fmaf(H2, w22.z, b2v.z)));
    o3 += fmaf(H0, w20.w, fmaf(H1, w21.w, fmaf(H2, w22.w, b2v.w)));
    const float4 res = {o0, o1, o2, o3};
    ((float4*)out)[nown * 16 + lr] = res;
  }
}

extern "C" void kernel_launch(void* const* d_in, const int* in_sizes, int n_in,
                              void* d_out, int out_size, void* d_ws, size_t ws_size,
                              hipStream_t stream) {
  const float* p     = (const float*)d_in[0];
  const float* x     = (const float*)d_in[1];
  const int*   idx   = (const int*)d_in[2];
  const float* Wq    = (const float*)d_in[3];
  const float* bq    = (const float*)d_in[4];
  const float* Wk    = (const float*)d_in[5];
  const float* bk    = (const float*)d_in[6];
  const float* Wv    = (const float*)d_in[7];
  const float* bv    = (const float*)d_in[8];
  const float* Wp1   = (const float*)d_in[9];
  const float* bp1   = (const float*)d_in[10];
  const float* gamma = (const float*)d_in[11];
  const float* beta  = (const float*)d_in[12];
  const float* Wp2   = (const float*)d_in[13];
  const float* bp2   = (const float*)d_in[14];
  float* out = (float*)d_out;

  char* w = (char*)d_ws;
  float* statsP       = (float*)w;                      // 9*1024 floats (planar), 36864 B
  unsigned short* kvq = (unsigned short*)(w + 65536);   // 25165824 B -> 25231360
  float* tq           = (float*)(w + 25231360);         // 1048576 B

  qkv_kernel<<<1024, 256, 0, stream>>>(x, Wq, Wk, Wv, bq, bk, bv, Wp2, bp2, p, idx,
                                       kvq, tq, statsP);
  attn_kernel<<<1024, 256, 0, stream>>>(p, idx, kvq, tq, statsP, Wp1, bp1, gamma, beta,
                                        Wp2, bp2, out);
}